// Round 19
// baseline (97.858 us; speedup 1.0000x reference)
//
#include <hip/hip_runtime.h>
#include <hip/hip_bf16.h>
#include <hip/hip_cooperative_groups.h>

namespace cg = cooperative_groups;

#define BB 64
#define NN 96
#define FF 16
#define HH 128
#define KK 64
#define LL 3
#define CUTOFF_F 10.0f
#define GAMMA_F 10.0f

#define AT 12

// Weight storage: f16, column-major [ch][k] per 16KB chunk (128ch x 64k),
// XOR-swizzled so the swizzled-read is bank-conflict-free after a LINEAR DMA:
#define SWZ(ch, k) ((ch) * 64 + ((k) ^ (((ch) & 7) << 3)))

typedef const __attribute__((address_space(1))) void* gp1_t;
typedef __attribute__((address_space(3))) void* lp3_t;
typedef _Float16 h8 __attribute__((ext_vector_type(8)));
typedef float f32x4 __attribute__((ext_vector_type(4)));

__device__ __forceinline__ void stage16(const _Float16* g, _Float16* lds, int tid)
{
    #pragma unroll
    for (int j = 0; j < 4; ++j) {
        const int u = j * 256 + tid;             // 16B units
        __builtin_amdgcn_global_load_lds((gp1_t)(g + (size_t)u * 8),
                                         (lp3_t)(lds + (size_t)u * 8), 16, 0, 0);
    }
}

#define BND(VM) do {                                                        \
    asm volatile("s_waitcnt vmcnt(" VM ") lgkmcnt(0)" ::: "memory");        \
    __builtin_amdgcn_s_barrier();                                           \
    __builtin_amdgcn_sched_barrier(0);                                      \
} while (0)

__device__ __forceinline__ float silu1(float v) { return v / (1.f + __expf(-v)); }

// B-fragment load from a swizzled chunk: ch = column, KB = k base (0 or 32)
#define LDB(WC, CH, KB) (*(const h8*)&(WC)[(CH) * 64 + (((KB) + lg8) ^ (((CH) & 7) << 3))])
#define MFMA(A, B, C) __builtin_amdgcn_mfma_f32_16x16x32_f16((A), (B), (C), 0, 0, 0)

// ---------------------------------------------------------------------------
// fused_kernel (cooperative, 512 blocks x 256 thr = 2 blocks/CU co-resident):
//  PRE-SYNC: local nv (ballot); stage R/X; distributed pre-work
//    bid<195:   one W3 row = (Wrbf@Wpair)@Wa1 (K-loop split over 2 halves)
//    195..206:  Wa2 -> f16 swizzled chunks
//    207..210:  Wo1 -> f16 swizzled chunks
//    211:       We -> Wec [ch][f] f16; zero out[0..63]
//  then distance table + exp S-phase (weight-independent).
//  grid.sync()
//  POST-SYNC: R18-verified MFMA chain (4-slot 16KB ring, counted vmcnt,
//  one s_barrier/phase, stage-after-barrier, epilogue 4/0).
// ---------------------------------------------------------------------------
__global__ __launch_bounds__(256, 2) void fused_kernel(
    const float* __restrict__ X, const float* __restrict__ R,
    const int* __restrict__ batch,
    const float* __restrict__ We, const float* __restrict__ be,
    const float* __restrict__ Wrbf, const float* __restrict__ brbf,
    const float* __restrict__ Wpair, const float* __restrict__ bpair,
    const float* __restrict__ Wa1, const float* __restrict__ ba1,
    const float* __restrict__ Wa2, const float* __restrict__ ba2,
    const float* __restrict__ Wo1, const float* __restrict__ bo1,
    const float* __restrict__ Wo2, const float* __restrict__ bo2,
    _Float16* __restrict__ W3c, float* __restrict__ c3,
    _Float16* __restrict__ Wa2c, _Float16* __restrict__ Wo1c,
    _Float16* __restrict__ Wec, float* __restrict__ out)
{
    __shared__ __align__(16) _Float16 wb[4 * 8192];       // 64KB weight ring
    __shared__ __align__(16) _Float16 sST[16][72];        // 2.3KB S (rows 12-15 zero)
    __shared__ __align__(16) _Float16 thbuf[2 * 16 * 136];// 8.7KB tbT+hbT (sD/sRf alias)
    __shared__ __align__(16) _Float16 sXh[16][32];        // 1KB X f16 (zero-padded)
    __shared__ float po[4][16];
    __shared__ float preW[3][HH];                         // 1.5KB pre-work scratch
    __shared__ int cpop[4];

    _Float16 (*tbT)[136] = (_Float16(*)[136])thbuf;
    _Float16 (*hbT)[136] = (_Float16(*)[136])(thbuf + 16 * 136);
    float* sD  = (float*)thbuf;          // 1152 floats
    float* sRf = sD + AT * NN;           // 288 floats

    const int tid  = threadIdx.x;
    const int lane = tid & 63;
    const int wv   = tid >> 6;
    const int l15  = lane & 15;
    const int lg   = lane >> 4;
    const int lg8  = lg * 8;
    const int lg4  = lg * 4;
    const int bid  = blockIdx.x;
    const int a0   = bid * AT;           // 96 % 12 == 0 -> block within one molecule
    const int b    = a0 / NN;
    const int lbase = a0 - b * NN;

    const int chA = 32 * wv + l15;
    const int chB = chA + 16;

    // ---- local valid-count (replaces cnt[] round-trip) ----
    {
        bool v = (tid < NN) && (batch[b * NN + tid] != -1);
        unsigned long long mb = __ballot(v);
        if ((tid & 63) == 0) cpop[wv] = __popcll(mb);
    }
    // ---- stage molecule R, X (f16 zero-padded) ----
    for (int t = tid; t < NN * 3; t += 256) sRf[t] = R[b * NN * 3 + t];
    for (int t = tid; t < 512; t += 256) {
        int row = t >> 5, col = t & 31;
        float v = (row < AT && col < FF) ? X[(a0 + row) * FF + col] : 0.f;
        sXh[row][col] = (_Float16)v;
    }
    __syncthreads();
    const int nv = cpop[0] + cpop[1] + cpop[2] + cpop[3];
    const float cb = (float)nv;

    // ---- distributed pre-work (bid uniform -> inner syncs are legal) ----
    if (bid < 195) {
        const int l = bid / 65, kk = bid % 65;
        const int kh = tid >> 7, h = tid & 127;
        const float* arow = (kk < KK) ? (Wrbf + (l * KK + kk) * HH) : (brbf + l * HH);
        const float* Wp = Wpair + l * HH * HH + h;
        float part = 0.f;
        #pragma unroll 8
        for (int m = 64 * kh; m < 64 * kh + 64; ++m) part += arow[m] * Wp[m * HH];
        preW[kh][h] = part;
        __syncthreads();
        if (kh == 0)
            preW[2][h] = preW[0][h] + preW[1][h] + ((kk == KK) ? bpair[l * HH + h] : 0.f);
        __syncthreads();
        const float* Wa = Wa1 + l * HH * HH + h;
        float p2 = 0.f;
        #pragma unroll 8
        for (int m = 64 * kh; m < 64 * kh + 64; ++m) p2 += preW[2][m] * Wa[m * HH];
        preW[kh][h] = p2;
        __syncthreads();
        if (kh == 0) {
            float a3 = preW[0][h] + preW[1][h];
            if (kk < KK) W3c[l * 8192 + SWZ(h, kk)] = (_Float16)a3;
            else         c3[l * HH + h] = a3;
        }
    } else if (bid < 207) {
        int ci = bid - 195;
        for (int e = tid; e < 4096; e += 256) {
            int E = ci * 4096 + e;                // Wa2 flat [l][k][ch]
            int l = E / 16384, r = E % 16384;
            int k = r >> 7, ch = r & 127;
            Wa2c[l * 16384 + (k >> 6) * 8192 + SWZ(ch, k & 63)] = (_Float16)Wa2[E];
        }
    } else if (bid < 211) {
        int ci = bid - 207;
        for (int e = tid; e < 4096; e += 256) {
            int E = ci * 4096 + e;                // Wo1 flat [k][ch]
            int k = E >> 7, ch = E & 127;
            Wo1c[(k >> 6) * 8192 + SWZ(ch, k & 63)] = (_Float16)Wo1[E];
        }
    } else if (bid == 211) {
        for (int e = tid; e < FF * HH; e += 256) {
            int f = e >> 7, ch = e & 127;         // We [f][ch] -> Wec [ch][f]
            Wec[ch * FF + f] = (_Float16)We[e];
        }
        if (tid < BB) out[tid] = 0.f;             // zero atomic targets
    }
    __syncthreads();

    // ---- distance table D[j][i] ----
    for (int e = tid; e < AT * NN; e += 256) {
        int j = e / NN, i = e - j * NN;
        float dx = sRf[i * 3 + 0] - sRf[(lbase + j) * 3 + 0];
        float dy = sRf[i * 3 + 1] - sRf[(lbase + j) * 3 + 1];
        float dz = sRf[i * 3 + 2] - sRf[(lbase + j) * 3 + 2];
        sD[e] = sqrtf(dx * dx + dy * dy + dz * dz);
    }
    __syncthreads();

    // ---- S-phase: sST[j][k] (f16); zero pad rows 12-15 ----
    {
        const float ck = (float)lane * (CUTOFF_F / (float)(KK - 1));
        #pragma unroll
        for (int r = 0; r < 3; ++r) {
            int j = 3 * wv + r;                  // wave-uniform
            if (lbase + j >= nv) { sST[j][lane] = (_Float16)0.f; continue; }
            const float* Dr = sD + j * NN;
            float acc = 0.f;
            for (int i = 0; i < nv; ++i) {
                float u = Dr[i] - ck;
                acc += __expf(-GAMMA_F * u * u);
            }
            sST[j][lane] = (_Float16)acc;
        }
        sST[12 + wv][lane] = (_Float16)0.f;
    }

    // ======== grid-wide sync: ws weights now visible everywhere ========
    cg::this_grid().sync();

    // ---- bias scalars + embedding B-frag (global loads OLDER than DMAs) ----
    const float be_a = be[chA], be_b = be[chB];
    const float bo1_a = bo1[chA], bo1_b = bo1[chB];
    const float wo2_a = Wo2[chA], wo2_b = Wo2[chB];
    const float bo2R = bo2[0];
    const float c3_0a = c3[chA], c3_0b = c3[chB];
    const float c3_1a = c3[HH + chA], c3_1b = c3[HH + chB];
    const float c3_2a = c3[2 * HH + chA], c3_2b = c3[2 * HH + chB];
    const float ba1_0a = ba1[chA], ba1_0b = ba1[chB];
    const float ba1_1a = ba1[HH + chA], ba1_1b = ba1[HH + chB];
    const float ba1_2a = ba1[2 * HH + chA], ba1_2b = ba1[2 * HH + chB];
    const float ba2_0a = ba2[chA], ba2_0b = ba2[chB];
    const float ba2_1a = ba2[HH + chA], ba2_1b = ba2[HH + chB];
    const float ba2_2a = ba2[2 * HH + chA], ba2_2b = ba2[2 * HH + chB];
    h8 weA = (h8)(_Float16)0.f, weB = (h8)(_Float16)0.f;
    if (lg < 2) {
        weA = *(const h8*)&Wec[chA * FF + lg8];
        weB = *(const h8*)&Wec[chB * FF + lg8];
    }

    // ---- prologue: issue chunks 0..3 ----
    stage16(W3c,          wb + 0 * 8192, tid);   // c0: W3[0]
    stage16(Wa2c,         wb + 1 * 8192, tid);   // c1: Wa2[0] k0-63
    stage16(Wa2c + 8192,  wb + 2 * 8192, tid);   // c2: Wa2[0] k64-127
    stage16(W3c + 8192,   wb + 3 * 8192, tid);   // c3: W3[1]

    // ---- embedding via MFMA: h = X@We + be (K=32, zero-padded) ----
    f32x4 hA, hB;
    {
        f32x4 z = {0.f, 0.f, 0.f, 0.f};
        h8 xa = *(const h8*)&sXh[l15][lg8];
        hA = MFMA(xa, weA, z);
        hB = MFMA(xa, weB, z);
        #pragma unroll
        for (int r = 0; r < 4; ++r) { hA[r] += be_a; hB[r] += be_b; }
    }

    BND("12");   // c0 landed (c1..c3 in flight)

    // ---- layers: 3 phases each ----
    #pragma unroll 1
    for (int l = 0; l < LL; ++l) {
        const float c3a  = (l == 0) ? c3_0a  : (l == 1) ? c3_1a  : c3_2a;
        const float c3b  = (l == 0) ? c3_0b  : (l == 1) ? c3_1b  : c3_2b;
        const float ba1a = (l == 0) ? ba1_0a : (l == 1) ? ba1_1a : ba1_2a;
        const float ba1b = (l == 0) ? ba1_0b : (l == 1) ? ba1_1b : ba1_2b;
        const float ba2a = (l == 0) ? ba2_0a : (l == 1) ? ba2_1a : ba2_2a;
        const float ba2b = (l == 0) ? ba2_0b : (l == 1) ? ba2_1b : ba2_2b;
        const int c_g1 = 3 * l;

        // GEMM1: agg = S @ W3[l]  (K=64)
        f32x4 accA, accB;
        {
            f32x4 z = {0.f, 0.f, 0.f, 0.f};
            const _Float16* wc = wb + (size_t)(c_g1 & 3) * 8192;
            h8 s0 = *(const h8*)&sST[l15][lg8];
            h8 s1 = *(const h8*)&sST[l15][32 + lg8];
            accA = MFMA(s0, LDB(wc, chA, 0), z);
            accA = MFMA(s1, LDB(wc, chA, 32), accA);
            accB = MFMA(s0, LDB(wc, chB, 0), z);
            accB = MFMA(s1, LDB(wc, chB, 32), accB);
        }
        {
            float biasA = cb * c3a + ba1a, biasB = cb * c3b + ba1b;
            #pragma unroll
            for (int r = 0; r < 4; ++r) {
                tbT[lg4 + r][chA] = (_Float16)silu1(accA[r] + biasA);
                tbT[lg4 + r][chB] = (_Float16)silu1(accB[r] + biasB);
            }
        }
        BND("8");
        { int i = c_g1 + 4; if (i < 11) {
            const _Float16* p = (i >= 9) ? (Wo1c + (size_t)(i - 9) * 8192)
                : ((i % 3) == 0 ? (W3c + (size_t)(i / 3) * 8192)
                                : (Wa2c + (size_t)(i / 3) * 16384 + (size_t)(i % 3 - 1) * 8192));
            stage16(p, wb + (size_t)(i & 3) * 8192, tid); } }

        // GEMM2a: h += t @ Wa2[l], k 0..63
        {
            const _Float16* wc = wb + (size_t)((c_g1 + 1) & 3) * 8192;
            h8 t0 = *(const h8*)&tbT[l15][lg8];
            h8 t1 = *(const h8*)&tbT[l15][32 + lg8];
            hA = MFMA(t0, LDB(wc, chA, 0), hA);
            hA = MFMA(t1, LDB(wc, chA, 32), hA);
            hB = MFMA(t0, LDB(wc, chB, 0), hB);
            hB = MFMA(t1, LDB(wc, chB, 32), hB);
        }
        BND("8");
        { int i = c_g1 + 5; if (i < 11) {
            const _Float16* p = (i >= 9) ? (Wo1c + (size_t)(i - 9) * 8192)
                : ((i % 3) == 0 ? (W3c + (size_t)(i / 3) * 8192)
                                : (Wa2c + (size_t)(i / 3) * 16384 + (size_t)(i % 3 - 1) * 8192));
            stage16(p, wb + (size_t)(i & 3) * 8192, tid); } }

        // GEMM2b: h += t @ Wa2[l], k 64..127
        {
            const _Float16* wc = wb + (size_t)((c_g1 + 2) & 3) * 8192;
            h8 t2 = *(const h8*)&tbT[l15][64 + lg8];
            h8 t3 = *(const h8*)&tbT[l15][96 + lg8];
            hA = MFMA(t2, LDB(wc, chA, 0), hA);
            hA = MFMA(t3, LDB(wc, chA, 32), hA);
            hB = MFMA(t2, LDB(wc, chB, 0), hB);
            hB = MFMA(t3, LDB(wc, chB, 32), hB);
        }
        #pragma unroll
        for (int r = 0; r < 4; ++r) { hA[r] += ba2a; hB[r] += ba2b; }
        if (l == LL - 1) {
            #pragma unroll
            for (int r = 0; r < 4; ++r) {
                hbT[lg4 + r][chA] = (_Float16)hA[r];
                hbT[lg4 + r][chB] = (_Float16)hB[r];
            }
        }
        BND("8");
        { int i = c_g1 + 6; if (i < 11) {
            const _Float16* p = (i >= 9) ? (Wo1c + (size_t)(i - 9) * 8192)
                : ((i % 3) == 0 ? (W3c + (size_t)(i / 3) * 8192)
                                : (Wa2c + (size_t)(i / 3) * 16384 + (size_t)(i % 3 - 1) * 8192));
            stage16(p, wb + (size_t)(i & 3) * 8192, tid); } }
    }

    // ---- head: O = h @ Wo1 (chunks 9,10 in slots 1,2) ----
    BND("4");    // c9 landed
    f32x4 oA, oB;
    {
        f32x4 z = {0.f, 0.f, 0.f, 0.f};
        const _Float16* wc = wb + 1 * 8192;
        h8 a0f = *(const h8*)&hbT[l15][lg8];
        h8 a1f = *(const h8*)&hbT[l15][32 + lg8];
        oA = MFMA(a0f, LDB(wc, chA, 0), z);
        oA = MFMA(a1f, LDB(wc, chA, 32), oA);
        oB = MFMA(a0f, LDB(wc, chB, 0), z);
        oB = MFMA(a1f, LDB(wc, chB, 32), oB);
    }
    BND("0");    // c10 landed
    {
        const _Float16* wc = wb + 2 * 8192;
        h8 a2f = *(const h8*)&hbT[l15][64 + lg8];
        h8 a3f = *(const h8*)&hbT[l15][96 + lg8];
        oA = MFMA(a2f, LDB(wc, chA, 0), oA);
        oA = MFMA(a3f, LDB(wc, chA, 32), oA);
        oB = MFMA(a2f, LDB(wc, chB, 0), oB);
        oB = MFMA(a3f, LDB(wc, chB, 32), oB);
    }

    // ---- epilogue: silu, Wo2 dot, reduce over channels ----
    float p[4];
    #pragma unroll
    for (int r = 0; r < 4; ++r)
        p[r] = silu1(oA[r] + bo1_a) * wo2_a + silu1(oB[r] + bo1_b) * wo2_b;
    #pragma unroll
    for (int r = 0; r < 4; ++r) {
        p[r] += __shfl_xor(p[r], 1);
        p[r] += __shfl_xor(p[r], 2);
        p[r] += __shfl_xor(p[r], 4);
        p[r] += __shfl_xor(p[r], 8);
    }
    if (l15 == 0) {
        #pragma unroll
        for (int r = 0; r < 4; ++r) po[wv][lg4 + r] = p[r];
    }
    __syncthreads();
    if (tid == 0) {
        float sum = 0.f;
        #pragma unroll
        for (int j = 0; j < AT; ++j) {
            if (lbase + j < nv)
                sum += po[0][j] + po[1][j] + po[2][j] + po[3][j] + bo2R;
        }
        atomicAdd(out + b, sum / cb);
    }
}

extern "C" void kernel_launch(void* const* d_in, const int* in_sizes, int n_in,
                              void* d_out, int out_size, void* d_ws, size_t ws_size,
                              hipStream_t stream) {
    const float* X     = (const float*)d_in[0];
    const float* R     = (const float*)d_in[1];
    const int*   batch = (const int*)  d_in[2];
    const float* We    = (const float*)d_in[3];
    const float* be    = (const float*)d_in[4];
    const float* Wrbf  = (const float*)d_in[5];
    const float* brbf  = (const float*)d_in[6];
    const float* Wpair = (const float*)d_in[7];
    const float* bpair = (const float*)d_in[8];
    const float* Wa1   = (const float*)d_in[9];
    const float* ba1   = (const float*)d_in[10];
    const float* Wa2   = (const float*)d_in[11];
    const float* ba2   = (const float*)d_in[12];
    const float* Wo1   = (const float*)d_in[13];
    const float* bo1   = (const float*)d_in[14];
    const float* Wo2   = (const float*)d_in[15];
    const float* bo2   = (const float*)d_in[16];

    char* wsb = (char*)d_ws;
    _Float16* W3c  = (_Float16*)wsb;                         // 24576 f16 = 49152 B
    _Float16* Wa2c = (_Float16*)(wsb + 49152);               // 49152 f16 = 98304 B
    _Float16* Wo1c = (_Float16*)(wsb + 147456);              // 16384 f16 = 32768 B
    _Float16* Wec  = (_Float16*)(wsb + 180224);              // 2048 f16  = 4096 B
    float*    c3   = (float*)(wsb + 184320);                 // 384 f32   = 1536 B
    float*    out  = (float*)d_out;

    void* kargs[] = {
        (void*)&X, (void*)&R, (void*)&batch, (void*)&We, (void*)&be,
        (void*)&Wrbf, (void*)&brbf, (void*)&Wpair, (void*)&bpair,
        (void*)&Wa1, (void*)&ba1, (void*)&Wa2, (void*)&ba2,
        (void*)&Wo1, (void*)&bo1, (void*)&Wo2, (void*)&bo2,
        (void*)&W3c, (void*)&c3, (void*)&Wa2c, (void*)&Wo1c,
        (void*)&Wec, (void*)&out
    };
    hipLaunchCooperativeKernel((const void*)fused_kernel,
                               dim3(BB * NN / AT), dim3(256), kargs, 0, stream);
}

// Round 20
// 30.939 us; speedup vs baseline: 3.1629x; 3.1629x over previous
//
#include <hip/hip_runtime.h>
#include <hip/hip_bf16.h>

#define BB 64
#define NN 96
#define FF 16
#define HH 128
#define KK 64
#define LL 3
#define CUTOFF_F 10.0f
#define GAMMA_F 10.0f

#define W3_BLOCKS 99
#define WA2_CP 12
#define WO1_CP 4
#define WE_CP 1

// Weight storage: f16, column-major [ch][k] per 16KB chunk (128ch x 64k),
// XOR-swizzled so the swizzled-read is bank-conflict-free after a LINEAR DMA:
#define SWZ(ch, k) ((ch) * 64 + ((k) ^ (((ch) & 7) << 3)))

// ---------------------------------------------------------------------------
// pre_kernel:
//   [0,99):    W3 = (Wrbf@Wpair)@Wa1 -> f16 [ch][k] swizzled chunks; row64->c3
//   [99,111):  Wa2c: f16 relayout of Wa2 (2 chunks/layer)
//   [111,115): Wo1c: same for Wo1
//   [115,116): Wec: f16 [ch][f] relayout of We; zero out[0..63]
// ---------------------------------------------------------------------------
__global__ __launch_bounds__(256) void pre_kernel(
    const float* __restrict__ Wrbf, const float* __restrict__ brbf,
    const float* __restrict__ Wpair, const float* __restrict__ bpair,
    const float* __restrict__ Wa1, const float* __restrict__ Wa2,
    const float* __restrict__ Wo1, const float* __restrict__ We,
    _Float16* __restrict__ W3c, float* __restrict__ c3,
    _Float16* __restrict__ Wa2c, _Float16* __restrict__ Wo1c,
    _Float16* __restrict__ Wec, float* __restrict__ out)
{
    const int bid = blockIdx.x;
    const int tid = threadIdx.x;
    if (bid < W3_BLOCKS) {
        __shared__ float sW2[2][HH];
        const int l    = bid / 33;
        const int r0   = (bid % 33) * 2;
        const int half = tid >> 7;
        const int h    = tid & 127;
        const int kk   = r0 + half;       // 0..65 (65 inactive)
        const bool active = (kk <= KK);
        if (active) {
            const float* Wp = Wpair + l * HH * HH + h;
            const float* arow;
            float acc;
            if (kk < KK) { arow = Wrbf + (l * KK + kk) * HH; acc = 0.f; }
            else         { arow = brbf + l * HH;             acc = bpair[l * HH + h]; }
            #pragma unroll 8
            for (int m = 0; m < HH; ++m) acc += arow[m] * Wp[m * HH];
            sW2[half][h] = acc;
        }
        __syncthreads();
        if (active) {
            const float* Wa = Wa1 + l * HH * HH + h;
            const float* row = sW2[half];
            float a3 = 0.f;
            #pragma unroll 8
            for (int m = 0; m < HH; ++m) a3 += row[m] * Wa[m * HH];
            if (kk < KK) W3c[l * 8192 + SWZ(h, kk)] = (_Float16)a3;
            else         c3[l * HH + h] = a3;
        }
    } else if (bid < W3_BLOCKS + WA2_CP) {
        int ci = bid - W3_BLOCKS;
        for (int e = tid; e < 4096; e += 256) {
            int E = ci * 4096 + e;                // Wa2 flat [l][k][ch]
            int l = E / 16384, r = E % 16384;
            int k = r >> 7, ch = r & 127;
            Wa2c[l * 16384 + (k >> 6) * 8192 + SWZ(ch, k & 63)] = (_Float16)Wa2[E];
        }
    } else if (bid < W3_BLOCKS + WA2_CP + WO1_CP) {
        int ci = bid - W3_BLOCKS - WA2_CP;
        for (int e = tid; e < 4096; e += 256) {
            int E = ci * 4096 + e;                // Wo1 flat [k][ch]
            int k = E >> 7, ch = E & 127;
            Wo1c[(k >> 6) * 8192 + SWZ(ch, k & 63)] = (_Float16)Wo1[E];
        }
    } else {
        for (int e = tid; e < FF * HH; e += 256) {
            int f = e >> 7, ch = e & 127;         // We [f][ch] -> Wec [ch][f]
            Wec[ch * FF + f] = (_Float16)We[e];
        }
        if (tid < BB) out[tid] = 0.f;             // zero atomic targets
    }
}

// ---------------------------------------------------------------------------
// chain_kernel: MFMA version, AT=12 (padded M=16), 256 thr (4 waves),
// grid 512 = 2 blocks/CU. nv via ballot (no cnt round-trip).
// Ring: 4 x 16KB slots; merged phases (G1 | G2a+G2b | head-both):
//   prologue c0..c3; BND(12); per layer: G1 -> BND(4)+stage(3l+4) ->
//   G2(both chunks) -> BND(4)+stage(3l+5,3l+6); head: BND(0), both chunks.
// Slot-overwrite safety verified chunk-by-chunk; >=2 phases DMA flight each.
// ---------------------------------------------------------------------------
#define AT 12

typedef const __attribute__((address_space(1))) void* gp1_t;
typedef __attribute__((address_space(3))) void* lp3_t;
typedef _Float16 h8 __attribute__((ext_vector_type(8)));
typedef float f32x4 __attribute__((ext_vector_type(4)));

__device__ __forceinline__ void stage16(const _Float16* g, _Float16* lds, int tid)
{
    #pragma unroll
    for (int j = 0; j < 4; ++j) {
        const int u = j * 256 + tid;             // 16B units
        __builtin_amdgcn_global_load_lds((gp1_t)(g + (size_t)u * 8),
                                         (lp3_t)(lds + (size_t)u * 8), 16, 0, 0);
    }
}

#define BND(VM) do {                                                        \
    asm volatile("s_waitcnt vmcnt(" VM ") lgkmcnt(0)" ::: "memory");        \
    __builtin_amdgcn_s_barrier();                                           \
    __builtin_amdgcn_sched_barrier(0);                                      \
} while (0)

__device__ __forceinline__ float silu1(float v) { return v / (1.f + __expf(-v)); }

// chunk i -> global source pointer
__device__ __forceinline__ const _Float16* chunk_src(int i, const _Float16* W3c,
    const _Float16* Wa2c, const _Float16* Wo1c)
{
    if (i >= 9) return Wo1c + (size_t)(i - 9) * 8192;
    if (i % 3 == 0) return W3c + (size_t)(i / 3) * 8192;
    return Wa2c + (size_t)(i / 3) * 16384 + (size_t)(i % 3 - 1) * 8192;
}

// B-fragment load from a swizzled chunk: ch = column, KB = k base (0 or 32)
#define LDB(WC, CH, KB) (*(const h8*)&(WC)[(CH) * 64 + (((KB) + lg8) ^ (((CH) & 7) << 3))])
#define MFMA(A, B, C) __builtin_amdgcn_mfma_f32_16x16x32_f16((A), (B), (C), 0, 0, 0)

__global__ __launch_bounds__(256, 2) void chain_kernel(
    const float* __restrict__ X, const float* __restrict__ R,
    const int* __restrict__ batch, const float* __restrict__ be,
    const float* __restrict__ ba1, const float* __restrict__ ba2,
    const float* __restrict__ bo1, const float* __restrict__ Wo2,
    const float* __restrict__ bo2, const _Float16* __restrict__ W3c,
    const _Float16* __restrict__ Wa2c, const _Float16* __restrict__ Wo1c,
    const _Float16* __restrict__ Wec,
    const float* __restrict__ c3, float* __restrict__ out)
{
    __shared__ __align__(16) _Float16 wb[4 * 8192];       // 64KB weight ring
    __shared__ __align__(16) _Float16 sST[16][72];        // 2.3KB S (rows 12-15 zero)
    __shared__ __align__(16) _Float16 thbuf[2 * 16 * 136];// 8.7KB tbT+hbT (sD/sRf alias)
    __shared__ __align__(16) _Float16 sXh[16][32];        // 1KB X f16 (zero-padded)
    __shared__ float po[4][16];
    __shared__ int cpop[4];

    _Float16 (*tbT)[136] = (_Float16(*)[136])thbuf;
    _Float16 (*hbT)[136] = (_Float16(*)[136])(thbuf + 16 * 136);
    float* sD  = (float*)thbuf;          // 1152 floats
    float* sRf = sD + AT * NN;           // 288 floats

    const int tid  = threadIdx.x;
    const int lane = tid & 63;
    const int wv   = tid >> 6;           // wave 0..3
    const int l15  = lane & 15;
    const int lg   = lane >> 4;          // lane group 0..3
    const int lg8  = lg * 8;
    const int lg4  = lg * 4;
    const int bid  = blockIdx.x;
    const int a0   = bid * AT;           // 96 % 12 == 0 -> block within one molecule
    const int b    = a0 / NN;
    const int lbase = a0 - b * NN;

    const int chA = 32 * wv + l15;       // this lane's two output columns
    const int chB = chA + 16;

    // ---- local valid-count (replaces cnt[] round-trip) ----
    {
        bool v = (tid < NN) && (batch[b * NN + tid] != -1);
        unsigned long long mb = __ballot(v);
        if ((tid & 63) == 0) cpop[wv] = __popcll(mb);
    }
    // ---- stage molecule R, X (f16, zero-padded rows/cols) ----
    for (int t = tid; t < NN * 3; t += 256) sRf[t] = R[b * NN * 3 + t];
    for (int t = tid; t < 512; t += 256) {
        int row = t >> 5, col = t & 31;
        float v = (row < AT && col < FF) ? X[(a0 + row) * FF + col] : 0.f;
        sXh[row][col] = (_Float16)v;
    }
    __syncthreads();
    const int nv = cpop[0] + cpop[1] + cpop[2] + cpop[3];
    const float cb = (float)nv;

    // ---- phase 1: distance table D[j][i] ----
    for (int e = tid; e < AT * NN; e += 256) {
        int j = e / NN, i = e - j * NN;
        float dx = sRf[i * 3 + 0] - sRf[(lbase + j) * 3 + 0];
        float dy = sRf[i * 3 + 1] - sRf[(lbase + j) * 3 + 1];
        float dz = sRf[i * 3 + 2] - sRf[(lbase + j) * 3 + 2];
        sD[e] = sqrtf(dx * dx + dy * dy + dz * dz);
    }
    __syncthreads();   // no DMA outstanding yet

    // ---- bias scalars + embedding B-frag (global loads OLDER than DMAs) ----
    const float be_a = be[chA], be_b = be[chB];
    const float bo1_a = bo1[chA], bo1_b = bo1[chB];
    const float wo2_a = Wo2[chA], wo2_b = Wo2[chB];
    const float bo2R = bo2[0];
    const float c3_0a = c3[chA], c3_0b = c3[chB];
    const float c3_1a = c3[HH + chA], c3_1b = c3[HH + chB];
    const float c3_2a = c3[2 * HH + chA], c3_2b = c3[2 * HH + chB];
    const float ba1_0a = ba1[chA], ba1_0b = ba1[chB];
    const float ba1_1a = ba1[HH + chA], ba1_1b = ba1[HH + chB];
    const float ba1_2a = ba1[2 * HH + chA], ba1_2b = ba1[2 * HH + chB];
    const float ba2_0a = ba2[chA], ba2_0b = ba2[chB];
    const float ba2_1a = ba2[HH + chA], ba2_1b = ba2[HH + chB];
    const float ba2_2a = ba2[2 * HH + chA], ba2_2b = ba2[2 * HH + chB];
    h8 weA = (h8)(_Float16)0.f, weB = (h8)(_Float16)0.f;
    if (lg < 2) {                         // k = lg8..lg8+7 < 16 real features
        weA = *(const h8*)&Wec[chA * FF + lg8];
        weB = *(const h8*)&Wec[chB * FF + lg8];
    }

    // ---- prologue: issue chunks 0..3 ----
    stage16(W3c,          wb + 0 * 8192, tid);   // c0: W3[0]
    stage16(Wa2c,         wb + 1 * 8192, tid);   // c1: Wa2[0] k0-63
    stage16(Wa2c + 8192,  wb + 2 * 8192, tid);   // c2: Wa2[0] k64-127
    stage16(W3c + 8192,   wb + 3 * 8192, tid);   // c3: W3[1]

    // ---- phase 2: sST[j][k] (f16); zero pad rows 12-15 ----
    {
        const float ck = (float)lane * (CUTOFF_F / (float)(KK - 1));
        #pragma unroll
        for (int r = 0; r < 3; ++r) {
            int j = 3 * wv + r;              // wave-uniform
            if (lbase + j >= nv) { sST[j][lane] = (_Float16)0.f; continue; }
            const float* Dr = sD + j * NN;
            float acc = 0.f;
            for (int i = 0; i < nv; ++i) {
                float u = Dr[i] - ck;
                acc += __expf(-GAMMA_F * u * u);
            }
            sST[j][lane] = (_Float16)acc;
        }
        sST[12 + wv][lane] = (_Float16)0.f;
    }

    // ---- embedding via MFMA: h = X@We + be (K=32, zero-padded) ----
    f32x4 hA, hB;
    {
        f32x4 z = {0.f, 0.f, 0.f, 0.f};
        h8 xa = *(const h8*)&sXh[l15][lg8];
        hA = MFMA(xa, weA, z);
        hB = MFMA(xa, weB, z);
        #pragma unroll
        for (int r = 0; r < 4; ++r) { hA[r] += be_a; hB[r] += be_b; }
    }

    BND("12");   // c0 landed (c1,c2,c3 in flight)

    // ---- layers: 2 phases each (G1 | G2-both) ----
    #pragma unroll 1
    for (int l = 0; l < LL; ++l) {
        const float c3a  = (l == 0) ? c3_0a  : (l == 1) ? c3_1a  : c3_2a;
        const float c3b  = (l == 0) ? c3_0b  : (l == 1) ? c3_1b  : c3_2b;
        const float ba1a = (l == 0) ? ba1_0a : (l == 1) ? ba1_1a : ba1_2a;
        const float ba1b = (l == 0) ? ba1_0b : (l == 1) ? ba1_1b : ba1_2b;
        const float ba2a = (l == 0) ? ba2_0a : (l == 1) ? ba2_1a : ba2_2a;
        const float ba2b = (l == 0) ? ba2_0b : (l == 1) ? ba2_1b : ba2_2b;
        const int c_g1 = 3 * l;

        // G1: agg = S @ W3[l]  (chunk 3l)
        f32x4 accA, accB;
        {
            f32x4 z = {0.f, 0.f, 0.f, 0.f};
            const _Float16* wc = wb + (size_t)(c_g1 & 3) * 8192;
            h8 s0 = *(const h8*)&sST[l15][lg8];
            h8 s1 = *(const h8*)&sST[l15][32 + lg8];
            accA = MFMA(s0, LDB(wc, chA, 0), z);
            accA = MFMA(s1, LDB(wc, chA, 32), accA);
            accB = MFMA(s0, LDB(wc, chB, 0), z);
            accB = MFMA(s1, LDB(wc, chB, 32), accB);
        }
        {   // bias + silu -> tbT (D layout: row = lg4+r, col = chA/chB)
            float biasA = cb * c3a + ba1a, biasB = cb * c3b + ba1b;
            #pragma unroll
            for (int r = 0; r < 4; ++r) {
                tbT[lg4 + r][chA] = (_Float16)silu1(accA[r] + biasA);
                tbT[lg4 + r][chB] = (_Float16)silu1(accB[r] + biasB);
            }
        }
        BND("4");   // chunks 3l+1, 3l+2 landed (one chunk stays in flight)
        { int i = c_g1 + 4; if (i < 11)
            stage16(chunk_src(i, W3c, Wa2c, Wo1c), wb + (size_t)(i & 3) * 8192, tid); }

        // G2: h += t @ Wa2[l]  (chunks 3l+1, 3l+2 in one phase)
        {
            const _Float16* wcA = wb + (size_t)((c_g1 + 1) & 3) * 8192;
            const _Float16* wcB2 = wb + (size_t)((c_g1 + 2) & 3) * 8192;
            h8 t0 = *(const h8*)&tbT[l15][lg8];
            h8 t1 = *(const h8*)&tbT[l15][32 + lg8];
            h8 t2 = *(const h8*)&tbT[l15][64 + lg8];
            h8 t3 = *(const h8*)&tbT[l15][96 + lg8];
            hA = MFMA(t0, LDB(wcA, chA, 0), hA);
            hA = MFMA(t1, LDB(wcA, chA, 32), hA);
            hB = MFMA(t0, LDB(wcA, chB, 0), hB);
            hB = MFMA(t1, LDB(wcA, chB, 32), hB);
            hA = MFMA(t2, LDB(wcB2, chA, 0), hA);
            hA = MFMA(t3, LDB(wcB2, chA, 32), hA);
            hB = MFMA(t2, LDB(wcB2, chB, 0), hB);
            hB = MFMA(t3, LDB(wcB2, chB, 32), hB);
        }
        #pragma unroll
        for (int r = 0; r < 4; ++r) { hA[r] += ba2a; hB[r] += ba2b; }
        if (l == LL - 1) {
            #pragma unroll
            for (int r = 0; r < 4; ++r) {
                hbT[lg4 + r][chA] = (_Float16)hA[r];
                hbT[lg4 + r][chB] = (_Float16)hB[r];
            }
        }
        if (l < LL - 1) {
            BND("4");   // chunk 3l+3 landed
            { int i = c_g1 + 5; if (i < 11)
                stage16(chunk_src(i, W3c, Wa2c, Wo1c), wb + (size_t)(i & 3) * 8192, tid); }
            { int i = c_g1 + 6; if (i < 11)
                stage16(chunk_src(i, W3c, Wa2c, Wo1c), wb + (size_t)(i & 3) * 8192, tid); }
        }
    }

    // ---- head: O = h @ Wo1 (chunks 9 slot1, 10 slot2; both in one phase) ----
    BND("0");
    f32x4 oA, oB;
    {
        f32x4 z = {0.f, 0.f, 0.f, 0.f};
        const _Float16* wc9 = wb + 1 * 8192;
        const _Float16* wc10 = wb + 2 * 8192;
        h8 a0f = *(const h8*)&hbT[l15][lg8];
        h8 a1f = *(const h8*)&hbT[l15][32 + lg8];
        h8 a2f = *(const h8*)&hbT[l15][64 + lg8];
        h8 a3f = *(const h8*)&hbT[l15][96 + lg8];
        oA = MFMA(a0f, LDB(wc9, chA, 0), z);
        oA = MFMA(a1f, LDB(wc9, chA, 32), oA);
        oB = MFMA(a0f, LDB(wc9, chB, 0), z);
        oB = MFMA(a1f, LDB(wc9, chB, 32), oB);
        oA = MFMA(a2f, LDB(wc10, chA, 0), oA);
        oA = MFMA(a3f, LDB(wc10, chA, 32), oA);
        oB = MFMA(a2f, LDB(wc10, chB, 0), oB);
        oB = MFMA(a3f, LDB(wc10, chB, 32), oB);
    }

    // ---- epilogue: silu, Wo2 dot, reduce over channels ----
    float p[4];
    #pragma unroll
    for (int r = 0; r < 4; ++r)
        p[r] = silu1(oA[r] + bo1_a) * wo2_a + silu1(oB[r] + bo1_b) * wo2_b;
    #pragma unroll
    for (int r = 0; r < 4; ++r) {
        p[r] += __shfl_xor(p[r], 1);
        p[r] += __shfl_xor(p[r], 2);
        p[r] += __shfl_xor(p[r], 4);
        p[r] += __shfl_xor(p[r], 8);
    }
    if (l15 == 0) {
        #pragma unroll
        for (int r = 0; r < 4; ++r) po[wv][lg4 + r] = p[r];  // atom = lg4+r
    }
    __syncthreads();
    if (tid == 0) {
        float sum = 0.f;
        #pragma unroll
        for (int j = 0; j < AT; ++j) {
            if (lbase + j < nv)
                sum += po[0][j] + po[1][j] + po[2][j] + po[3][j] + bo2R;
        }
        atomicAdd(out + b, sum / cb);
    }
}

extern "C" void kernel_launch(void* const* d_in, const int* in_sizes, int n_in,
                              void* d_out, int out_size, void* d_ws, size_t ws_size,
                              hipStream_t stream) {
    const float* X     = (const float*)d_in[0];
    const float* R     = (const float*)d_in[1];
    const int*   batch = (const int*)  d_in[2];
    const float* We    = (const float*)d_in[3];
    const float* be    = (const float*)d_in[4];
    const float* Wrbf  = (const float*)d_in[5];
    const float* brbf  = (const float*)d_in[6];
    const float* Wpair = (const float*)d_in[7];
    const float* bpair = (const float*)d_in[8];
    const float* Wa1   = (const float*)d_in[9];
    const float* ba1   = (const float*)d_in[10];
    const float* Wa2   = (const float*)d_in[11];
    const float* ba2   = (const float*)d_in[12];
    const float* Wo1   = (const float*)d_in[13];
    const float* bo1   = (const float*)d_in[14];
    const float* Wo2   = (const float*)d_in[15];
    const float* bo2   = (const float*)d_in[16];

    char* wsb = (char*)d_ws;
    _Float16* W3c  = (_Float16*)wsb;                         // 24576 f16 = 49152 B
    _Float16* Wa2c = (_Float16*)(wsb + 49152);               // 49152 f16 = 98304 B
    _Float16* Wo1c = (_Float16*)(wsb + 147456);              // 16384 f16 = 32768 B
    _Float16* Wec  = (_Float16*)(wsb + 180224);              // 2048 f16  = 4096 B
    float*    c3   = (float*)(wsb + 184320);                 // 384 f32   = 1536 B
    float*    out  = (float*)d_out;

    hipLaunchKernelGGL(pre_kernel,
                       dim3(W3_BLOCKS + WA2_CP + WO1_CP + WE_CP), dim3(256),
                       0, stream, Wrbf, brbf, Wpair, bpair, Wa1, Wa2, Wo1, We,
                       W3c, c3, Wa2c, Wo1c, Wec, out);
    hipLaunchKernelGGL(chain_kernel, dim3(BB * NN / AT), dim3(256), 0, stream,
                       X, R, batch, be, ba1, ba2, bo1, Wo2, bo2,
                       W3c, Wa2c, Wo1c, Wec, c3, out);
}

// Round 21
// 28.230 us; speedup vs baseline: 3.4665x; 1.0960x over previous
//
#include <hip/hip_runtime.h>
#include <hip/hip_bf16.h>

#define BB 64
#define NN 96
#define FF 16
#define HH 128
#define KK 64
#define LL 3
#define CUTOFF_F 10.0f
#define GAMMA_F 10.0f

#define W3_BLOCKS 195         // 3 layers * 65 rows, one row per block (split-K)
#define WA2_CP 12
#define WO1_CP 4
#define WE_CP 1

// Weight storage: f16, column-major [ch][k] per 16KB chunk (128ch x 64k),
// XOR-swizzled so the swizzled-read is bank-conflict-free after a LINEAR DMA:
#define SWZ(ch, k) ((ch) * 64 + ((k) ^ (((ch) & 7) << 3)))

// ---------------------------------------------------------------------------
// pre_kernel:
//   [0,195):   one W3 row = (Wrbf@Wpair)@Wa1 per block, K split over 2 thread
//              halves + LDS reduce (R19-verified logic); row 64 -> c3 fp32.
//   [195,207): Wa2c: f16 swizzled relayout of Wa2
//   [207,211): Wo1c: same for Wo1
//   [211]:     Wec: f16 [ch][f] relayout of We; zero out[0..63]
// ---------------------------------------------------------------------------
__global__ __launch_bounds__(256) void pre_kernel(
    const float* __restrict__ Wrbf, const float* __restrict__ brbf,
    const float* __restrict__ Wpair, const float* __restrict__ bpair,
    const float* __restrict__ Wa1, const float* __restrict__ Wa2,
    const float* __restrict__ Wo1, const float* __restrict__ We,
    _Float16* __restrict__ W3c, float* __restrict__ c3,
    _Float16* __restrict__ Wa2c, _Float16* __restrict__ Wo1c,
    _Float16* __restrict__ Wec, float* __restrict__ out)
{
    const int bid = blockIdx.x;
    const int tid = threadIdx.x;
    if (bid < W3_BLOCKS) {
        __shared__ float preW[3][HH];
        const int l = bid / 65, kk = bid % 65;
        const int kh = tid >> 7, h = tid & 127;
        const float* arow = (kk < KK) ? (Wrbf + (l * KK + kk) * HH) : (brbf + l * HH);
        const float* Wp = Wpair + l * HH * HH + h;
        float part = 0.f;
        #pragma unroll 8
        for (int m = 64 * kh; m < 64 * kh + 64; ++m) part += arow[m] * Wp[m * HH];
        preW[kh][h] = part;
        __syncthreads();
        if (kh == 0)
            preW[2][h] = preW[0][h] + preW[1][h] + ((kk == KK) ? bpair[l * HH + h] : 0.f);
        __syncthreads();
        const float* Wa = Wa1 + l * HH * HH + h;
        float p2 = 0.f;
        #pragma unroll 8
        for (int m = 64 * kh; m < 64 * kh + 64; ++m) p2 += preW[2][m] * Wa[m * HH];
        preW[kh][h] = p2;
        __syncthreads();
        if (kh == 0) {
            float a3 = preW[0][h] + preW[1][h];
            if (kk < KK) W3c[l * 8192 + SWZ(h, kk)] = (_Float16)a3;
            else         c3[l * HH + h] = a3;
        }
    } else if (bid < W3_BLOCKS + WA2_CP) {
        int ci = bid - W3_BLOCKS;
        for (int e = tid; e < 4096; e += 256) {
            int E = ci * 4096 + e;                // Wa2 flat [l][k][ch]
            int l = E / 16384, r = E % 16384;
            int k = r >> 7, ch = r & 127;
            Wa2c[l * 16384 + (k >> 6) * 8192 + SWZ(ch, k & 63)] = (_Float16)Wa2[E];
        }
    } else if (bid < W3_BLOCKS + WA2_CP + WO1_CP) {
        int ci = bid - W3_BLOCKS - WA2_CP;
        for (int e = tid; e < 4096; e += 256) {
            int E = ci * 4096 + e;                // Wo1 flat [k][ch]
            int k = E >> 7, ch = E & 127;
            Wo1c[(k >> 6) * 8192 + SWZ(ch, k & 63)] = (_Float16)Wo1[E];
        }
    } else {
        for (int e = tid; e < FF * HH; e += 256) {
            int f = e >> 7, ch = e & 127;         // We [f][ch] -> Wec [ch][f]
            Wec[ch * FF + f] = (_Float16)We[e];
        }
        if (tid < BB) out[tid] = 0.f;             // zero atomic targets
    }
}

// ---------------------------------------------------------------------------
// chain_kernel: unchanged from R20 (passing). MFMA, AT=12 (padded M=16),
// 256 thr (4 waves), grid 512 = 2 blocks/CU, nv via ballot, 4-slot 16KB ring,
// merged phases, counted vmcnt, one s_barrier/phase, stage-after-barrier.
// ---------------------------------------------------------------------------
#define AT 12

typedef const __attribute__((address_space(1))) void* gp1_t;
typedef __attribute__((address_space(3))) void* lp3_t;
typedef _Float16 h8 __attribute__((ext_vector_type(8)));
typedef float f32x4 __attribute__((ext_vector_type(4)));

__device__ __forceinline__ void stage16(const _Float16* g, _Float16* lds, int tid)
{
    #pragma unroll
    for (int j = 0; j < 4; ++j) {
        const int u = j * 256 + tid;             // 16B units
        __builtin_amdgcn_global_load_lds((gp1_t)(g + (size_t)u * 8),
                                         (lp3_t)(lds + (size_t)u * 8), 16, 0, 0);
    }
}

#define BND(VM) do {                                                        \
    asm volatile("s_waitcnt vmcnt(" VM ") lgkmcnt(0)" ::: "memory");        \
    __builtin_amdgcn_s_barrier();                                           \
    __builtin_amdgcn_sched_barrier(0);                                      \
} while (0)

__device__ __forceinline__ float silu1(float v) { return v / (1.f + __expf(-v)); }

// chunk i -> global source pointer
__device__ __forceinline__ const _Float16* chunk_src(int i, const _Float16* W3c,
    const _Float16* Wa2c, const _Float16* Wo1c)
{
    if (i >= 9) return Wo1c + (size_t)(i - 9) * 8192;
    if (i % 3 == 0) return W3c + (size_t)(i / 3) * 8192;
    return Wa2c + (size_t)(i / 3) * 16384 + (size_t)(i % 3 - 1) * 8192;
}

// B-fragment load from a swizzled chunk: ch = column, KB = k base (0 or 32)
#define LDB(WC, CH, KB) (*(const h8*)&(WC)[(CH) * 64 + (((KB) + lg8) ^ (((CH) & 7) << 3))])
#define MFMA(A, B, C) __builtin_amdgcn_mfma_f32_16x16x32_f16((A), (B), (C), 0, 0, 0)

__global__ __launch_bounds__(256, 2) void chain_kernel(
    const float* __restrict__ X, const float* __restrict__ R,
    const int* __restrict__ batch, const float* __restrict__ be,
    const float* __restrict__ ba1, const float* __restrict__ ba2,
    const float* __restrict__ bo1, const float* __restrict__ Wo2,
    const float* __restrict__ bo2, const _Float16* __restrict__ W3c,
    const _Float16* __restrict__ Wa2c, const _Float16* __restrict__ Wo1c,
    const _Float16* __restrict__ Wec,
    const float* __restrict__ c3, float* __restrict__ out)
{
    __shared__ __align__(16) _Float16 wb[4 * 8192];       // 64KB weight ring
    __shared__ __align__(16) _Float16 sST[16][72];        // 2.3KB S (rows 12-15 zero)
    __shared__ __align__(16) _Float16 thbuf[2 * 16 * 136];// 8.7KB tbT+hbT (sD/sRf alias)
    __shared__ __align__(16) _Float16 sXh[16][32];        // 1KB X f16 (zero-padded)
    __shared__ float po[4][16];
    __shared__ int cpop[4];

    _Float16 (*tbT)[136] = (_Float16(*)[136])thbuf;
    _Float16 (*hbT)[136] = (_Float16(*)[136])(thbuf + 16 * 136);
    float* sD  = (float*)thbuf;          // 1152 floats
    float* sRf = sD + AT * NN;           // 288 floats

    const int tid  = threadIdx.x;
    const int lane = tid & 63;
    const int wv   = tid >> 6;           // wave 0..3
    const int l15  = lane & 15;
    const int lg   = lane >> 4;          // lane group 0..3
    const int lg8  = lg * 8;
    const int lg4  = lg * 4;
    const int bid  = blockIdx.x;
    const int a0   = bid * AT;           // 96 % 12 == 0 -> block within one molecule
    const int b    = a0 / NN;
    const int lbase = a0 - b * NN;

    const int chA = 32 * wv + l15;       // this lane's two output columns
    const int chB = chA + 16;

    // ---- local valid-count ----
    {
        bool v = (tid < NN) && (batch[b * NN + tid] != -1);
        unsigned long long mb = __ballot(v);
        if ((tid & 63) == 0) cpop[wv] = __popcll(mb);
    }
    // ---- stage molecule R, X (f16, zero-padded rows/cols) ----
    for (int t = tid; t < NN * 3; t += 256) sRf[t] = R[b * NN * 3 + t];
    for (int t = tid; t < 512; t += 256) {
        int row = t >> 5, col = t & 31;
        float v = (row < AT && col < FF) ? X[(a0 + row) * FF + col] : 0.f;
        sXh[row][col] = (_Float16)v;
    }
    __syncthreads();
    const int nv = cpop[0] + cpop[1] + cpop[2] + cpop[3];
    const float cb = (float)nv;

    // ---- phase 1: distance table D[j][i] ----
    for (int e = tid; e < AT * NN; e += 256) {
        int j = e / NN, i = e - j * NN;
        float dx = sRf[i * 3 + 0] - sRf[(lbase + j) * 3 + 0];
        float dy = sRf[i * 3 + 1] - sRf[(lbase + j) * 3 + 1];
        float dz = sRf[i * 3 + 2] - sRf[(lbase + j) * 3 + 2];
        sD[e] = sqrtf(dx * dx + dy * dy + dz * dz);
    }
    __syncthreads();   // no DMA outstanding yet

    // ---- bias scalars + embedding B-frag (global loads OLDER than DMAs) ----
    const float be_a = be[chA], be_b = be[chB];
    const float bo1_a = bo1[chA], bo1_b = bo1[chB];
    const float wo2_a = Wo2[chA], wo2_b = Wo2[chB];
    const float bo2R = bo2[0];
    const float c3_0a = c3[chA], c3_0b = c3[chB];
    const float c3_1a = c3[HH + chA], c3_1b = c3[HH + chB];
    const float c3_2a = c3[2 * HH + chA], c3_2b = c3[2 * HH + chB];
    const float ba1_0a = ba1[chA], ba1_0b = ba1[chB];
    const float ba1_1a = ba1[HH + chA], ba1_1b = ba1[HH + chB];
    const float ba1_2a = ba1[2 * HH + chA], ba1_2b = ba1[2 * HH + chB];
    const float ba2_0a = ba2[chA], ba2_0b = ba2[chB];
    const float ba2_1a = ba2[HH + chA], ba2_1b = ba2[HH + chB];
    const float ba2_2a = ba2[2 * HH + chA], ba2_2b = ba2[2 * HH + chB];
    h8 weA = (h8)(_Float16)0.f, weB = (h8)(_Float16)0.f;
    if (lg < 2) {                         // k = lg8..lg8+7 < 16 real features
        weA = *(const h8*)&Wec[chA * FF + lg8];
        weB = *(const h8*)&Wec[chB * FF + lg8];
    }

    // ---- prologue: issue chunks 0..3 ----
    stage16(W3c,          wb + 0 * 8192, tid);   // c0: W3[0]
    stage16(Wa2c,         wb + 1 * 8192, tid);   // c1: Wa2[0] k0-63
    stage16(Wa2c + 8192,  wb + 2 * 8192, tid);   // c2: Wa2[0] k64-127
    stage16(W3c + 8192,   wb + 3 * 8192, tid);   // c3: W3[1]

    // ---- phase 2: sST[j][k] (f16); zero pad rows 12-15 ----
    {
        const float ck = (float)lane * (CUTOFF_F / (float)(KK - 1));
        #pragma unroll
        for (int r = 0; r < 3; ++r) {
            int j = 3 * wv + r;              // wave-uniform
            if (lbase + j >= nv) { sST[j][lane] = (_Float16)0.f; continue; }
            const float* Dr = sD + j * NN;
            float acc = 0.f;
            for (int i = 0; i < nv; ++i) {
                float u = Dr[i] - ck;
                acc += __expf(-GAMMA_F * u * u);
            }
            sST[j][lane] = (_Float16)acc;
        }
        sST[12 + wv][lane] = (_Float16)0.f;
    }

    // ---- embedding via MFMA: h = X@We + be (K=32, zero-padded) ----
    f32x4 hA, hB;
    {
        f32x4 z = {0.f, 0.f, 0.f, 0.f};
        h8 xa = *(const h8*)&sXh[l15][lg8];
        hA = MFMA(xa, weA, z);
        hB = MFMA(xa, weB, z);
        #pragma unroll
        for (int r = 0; r < 4; ++r) { hA[r] += be_a; hB[r] += be_b; }
    }

    BND("12");   // c0 landed (c1,c2,c3 in flight)

    // ---- layers: 2 phases each (G1 | G2-both) ----
    #pragma unroll 1
    for (int l = 0; l < LL; ++l) {
        const float c3a  = (l == 0) ? c3_0a  : (l == 1) ? c3_1a  : c3_2a;
        const float c3b  = (l == 0) ? c3_0b  : (l == 1) ? c3_1b  : c3_2b;
        const float ba1a = (l == 0) ? ba1_0a : (l == 1) ? ba1_1a : ba1_2a;
        const float ba1b = (l == 0) ? ba1_0b : (l == 1) ? ba1_1b : ba1_2b;
        const float ba2a = (l == 0) ? ba2_0a : (l == 1) ? ba2_1a : ba2_2a;
        const float ba2b = (l == 0) ? ba2_0b : (l == 1) ? ba2_1b : ba2_2b;
        const int c_g1 = 3 * l;

        // G1: agg = S @ W3[l]  (chunk 3l)
        f32x4 accA, accB;
        {
            f32x4 z = {0.f, 0.f, 0.f, 0.f};
            const _Float16* wc = wb + (size_t)(c_g1 & 3) * 8192;
            h8 s0 = *(const h8*)&sST[l15][lg8];
            h8 s1 = *(const h8*)&sST[l15][32 + lg8];
            accA = MFMA(s0, LDB(wc, chA, 0), z);
            accA = MFMA(s1, LDB(wc, chA, 32), accA);
            accB = MFMA(s0, LDB(wc, chB, 0), z);
            accB = MFMA(s1, LDB(wc, chB, 32), accB);
        }
        {   // bias + silu -> tbT (D layout: row = lg4+r, col = chA/chB)
            float biasA = cb * c3a + ba1a, biasB = cb * c3b + ba1b;
            #pragma unroll
            for (int r = 0; r < 4; ++r) {
                tbT[lg4 + r][chA] = (_Float16)silu1(accA[r] + biasA);
                tbT[lg4 + r][chB] = (_Float16)silu1(accB[r] + biasB);
            }
        }
        BND("4");   // chunks 3l+1, 3l+2 landed (one chunk stays in flight)
        { int i = c_g1 + 4; if (i < 11)
            stage16(chunk_src(i, W3c, Wa2c, Wo1c), wb + (size_t)(i & 3) * 8192, tid); }

        // G2: h += t @ Wa2[l]  (chunks 3l+1, 3l+2 in one phase)
        {
            const _Float16* wcA = wb + (size_t)((c_g1 + 1) & 3) * 8192;
            const _Float16* wcB2 = wb + (size_t)((c_g1 + 2) & 3) * 8192;
            h8 t0 = *(const h8*)&tbT[l15][lg8];
            h8 t1 = *(const h8*)&tbT[l15][32 + lg8];
            h8 t2 = *(const h8*)&tbT[l15][64 + lg8];
            h8 t3 = *(const h8*)&tbT[l15][96 + lg8];
            hA = MFMA(t0, LDB(wcA, chA, 0), hA);
            hA = MFMA(t1, LDB(wcA, chA, 32), hA);
            hB = MFMA(t0, LDB(wcA, chB, 0), hB);
            hB = MFMA(t1, LDB(wcA, chB, 32), hB);
            hA = MFMA(t2, LDB(wcB2, chA, 0), hA);
            hA = MFMA(t3, LDB(wcB2, chA, 32), hA);
            hB = MFMA(t2, LDB(wcB2, chB, 0), hB);
            hB = MFMA(t3, LDB(wcB2, chB, 32), hB);
        }
        #pragma unroll
        for (int r = 0; r < 4; ++r) { hA[r] += ba2a; hB[r] += ba2b; }
        if (l == LL - 1) {
            #pragma unroll
            for (int r = 0; r < 4; ++r) {
                hbT[lg4 + r][chA] = (_Float16)hA[r];
                hbT[lg4 + r][chB] = (_Float16)hB[r];
            }
        }
        if (l < LL - 1) {
            BND("4");   // chunk 3l+3 landed
            { int i = c_g1 + 5; if (i < 11)
                stage16(chunk_src(i, W3c, Wa2c, Wo1c), wb + (size_t)(i & 3) * 8192, tid); }
            { int i = c_g1 + 6; if (i < 11)
                stage16(chunk_src(i, W3c, Wa2c, Wo1c), wb + (size_t)(i & 3) * 8192, tid); }
        }
    }

    // ---- head: O = h @ Wo1 (chunks 9 slot1, 10 slot2; both in one phase) ----
    BND("0");
    f32x4 oA, oB;
    {
        f32x4 z = {0.f, 0.f, 0.f, 0.f};
        const _Float16* wc9 = wb + 1 * 8192;
        const _Float16* wc10 = wb + 2 * 8192;
        h8 a0f = *(const h8*)&hbT[l15][lg8];
        h8 a1f = *(const h8*)&hbT[l15][32 + lg8];
        h8 a2f = *(const h8*)&hbT[l15][64 + lg8];
        h8 a3f = *(const h8*)&hbT[l15][96 + lg8];
        oA = MFMA(a0f, LDB(wc9, chA, 0), z);
        oA = MFMA(a1f, LDB(wc9, chA, 32), oA);
        oB = MFMA(a0f, LDB(wc9, chB, 0), z);
        oB = MFMA(a1f, LDB(wc9, chB, 32), oB);
        oA = MFMA(a2f, LDB(wc10, chA, 0), oA);
        oA = MFMA(a3f, LDB(wc10, chA, 32), oA);
        oB = MFMA(a2f, LDB(wc10, chB, 0), oB);
        oB = MFMA(a3f, LDB(wc10, chB, 32), oB);
    }

    // ---- epilogue: silu, Wo2 dot, reduce over channels ----
    float p[4];
    #pragma unroll
    for (int r = 0; r < 4; ++r)
        p[r] = silu1(oA[r] + bo1_a) * wo2_a + silu1(oB[r] + bo1_b) * wo2_b;
    #pragma unroll
    for (int r = 0; r < 4; ++r) {
        p[r] += __shfl_xor(p[r], 1);
        p[r] += __shfl_xor(p[r], 2);
        p[r] += __shfl_xor(p[r], 4);
        p[r] += __shfl_xor(p[r], 8);
    }
    if (l15 == 0) {
        #pragma unroll
        for (int r = 0; r < 4; ++r) po[wv][lg4 + r] = p[r];  // atom = lg4+r
    }
    __syncthreads();
    if (tid == 0) {
        float sum = 0.f;
        #pragma unroll
        for (int j = 0; j < AT; ++j) {
            if (lbase + j < nv)
                sum += po[0][j] + po[1][j] + po[2][j] + po[3][j] + bo2R;
        }
        atomicAdd(out + b, sum / cb);
    }
}

extern "C" void kernel_launch(void* const* d_in, const int* in_sizes, int n_in,
                              void* d_out, int out_size, void* d_ws, size_t ws_size,
                              hipStream_t stream) {
    const float* X     = (const float*)d_in[0];
    const float* R     = (const float*)d_in[1];
    const int*   batch = (const int*)  d_in[2];
    const float* We    = (const float*)d_in[3];
    const float* be    = (const float*)d_in[4];
    const float* Wrbf  = (const float*)d_in[5];
    const float* brbf  = (const float*)d_in[6];
    const float* Wpair = (const float*)d_in[7];
    const float* bpair = (const float*)d_in[8];
    const float* Wa1   = (const float*)d_in[9];
    const float* ba1   = (const float*)d_in[10];
    const float* Wa2   = (const float*)d_in[11];
    const float* ba2   = (const float*)d_in[12];
    const float* Wo1   = (const float*)d_in[13];
    const float* bo1   = (const float*)d_in[14];
    const float* Wo2   = (const float*)d_in[15];
    const float* bo2   = (const float*)d_in[16];

    char* wsb = (char*)d_ws;
    _Float16* W3c  = (_Float16*)wsb;                         // 24576 f16 = 49152 B
    _Float16* Wa2c = (_Float16*)(wsb + 49152);               // 49152 f16 = 98304 B
    _Float16* Wo1c = (_Float16*)(wsb + 147456);              // 16384 f16 = 32768 B
    _Float16* Wec  = (_Float16*)(wsb + 180224);              // 2048 f16  = 4096 B
    float*    c3   = (float*)(wsb + 184320);                 // 384 f32   = 1536 B
    float*    out  = (float*)d_out;

    hipLaunchKernelGGL(pre_kernel,
                       dim3(W3_BLOCKS + WA2_CP + WO1_CP + WE_CP), dim3(256),
                       0, stream, Wrbf, brbf, Wpair, bpair, Wa1, Wa2, Wo1, We,
                       W3c, c3, Wa2c, Wo1c, Wec, out);
    hipLaunchKernelGGL(chain_kernel, dim3(BB * NN / AT), dim3(256), 0, stream,
                       X, R, batch, be, ba1, ba2, bo1, Wo2, bo2,
                       W3c, Wa2c, Wo1c, Wec, c3, out);
}

// Round 22
// 27.062 us; speedup vs baseline: 3.6161x; 1.0431x over previous
//
#include <hip/hip_runtime.h>
#include <hip/hip_bf16.h>

#define BB 64
#define NN 96
#define FF 16
#define HH 128
#define KK 64
#define LL 3
#define CUTOFF_F 10.0f
#define GAMMA_F 10.0f

#define W3_BLOCKS 195         // 3 layers * 65 rows, one row per block (split-K x4)
#define WA2_CP 12
#define WO1_CP 4
#define WE_CP 1

// Weight storage: f16, column-major [ch][k] per 16KB chunk (128ch x 64k),
// XOR-swizzled so the swizzled-read is bank-conflict-free after a LINEAR DMA:
#define SWZ(ch, k) ((ch) * 64 + ((k) ^ (((ch) & 7) << 3)))

// ---------------------------------------------------------------------------
// pre_kernel (512 threads):
//   [0,195):   one W3 row = (Wrbf@Wpair)@Wa1 per block, K split over 4 thread
//              quarters + LDS reduce; row 64 -> c3 fp32.
//   [195,207): Wa2c: f16 swizzled relayout of Wa2
//   [207,211): Wo1c: same for Wo1
//   [211]:     Wec: f16 [ch][f] relayout of We; zero out[0..63]
// ---------------------------------------------------------------------------
__global__ __launch_bounds__(512) void pre_kernel(
    const float* __restrict__ Wrbf, const float* __restrict__ brbf,
    const float* __restrict__ Wpair, const float* __restrict__ bpair,
    const float* __restrict__ Wa1, const float* __restrict__ Wa2,
    const float* __restrict__ Wo1, const float* __restrict__ We,
    _Float16* __restrict__ W3c, float* __restrict__ c3,
    _Float16* __restrict__ Wa2c, _Float16* __restrict__ Wo1c,
    _Float16* __restrict__ Wec, float* __restrict__ out)
{
    const int bid = blockIdx.x;
    const int tid = threadIdx.x;
    if (bid < W3_BLOCKS) {
        __shared__ float preW[4][HH];
        __shared__ float rowW[HH];
        const int l = bid / 65, kk = bid % 65;
        const int kq = tid >> 7, h = tid & 127;   // 4 K-quarters x 128 channels
        const float* arow = (kk < KK) ? (Wrbf + (l * KK + kk) * HH) : (brbf + l * HH);
        const float* Wp = Wpair + l * HH * HH + h;
        float part = 0.f;
        #pragma unroll 8
        for (int m = 32 * kq; m < 32 * kq + 32; ++m) part += arow[m] * Wp[m * HH];
        preW[kq][h] = part;
        __syncthreads();
        if (kq == 0)
            rowW[h] = preW[0][h] + preW[1][h] + preW[2][h] + preW[3][h]
                    + ((kk == KK) ? bpair[l * HH + h] : 0.f);
        __syncthreads();
        const float* Wa = Wa1 + l * HH * HH + h;
        float p2 = 0.f;
        #pragma unroll 8
        for (int m = 32 * kq; m < 32 * kq + 32; ++m) p2 += rowW[m] * Wa[m * HH];
        preW[kq][h] = p2;
        __syncthreads();
        if (kq == 0) {
            float a3 = preW[0][h] + preW[1][h] + preW[2][h] + preW[3][h];
            if (kk < KK) W3c[l * 8192 + SWZ(h, kk)] = (_Float16)a3;
            else         c3[l * HH + h] = a3;
        }
    } else if (bid < W3_BLOCKS + WA2_CP) {
        int ci = bid - W3_BLOCKS;
        for (int e = tid; e < 4096; e += 512) {
            int E = ci * 4096 + e;                // Wa2 flat [l][k][ch]
            int l = E / 16384, r = E % 16384;
            int k = r >> 7, ch = r & 127;
            Wa2c[l * 16384 + (k >> 6) * 8192 + SWZ(ch, k & 63)] = (_Float16)Wa2[E];
        }
    } else if (bid < W3_BLOCKS + WA2_CP + WO1_CP) {
        int ci = bid - W3_BLOCKS - WA2_CP;
        for (int e = tid; e < 4096; e += 512) {
            int E = ci * 4096 + e;                // Wo1 flat [k][ch]
            int k = E >> 7, ch = E & 127;
            Wo1c[(k >> 6) * 8192 + SWZ(ch, k & 63)] = (_Float16)Wo1[E];
        }
    } else {
        for (int e = tid; e < FF * HH; e += 512) {
            int f = e >> 7, ch = e & 127;         // We [f][ch] -> Wec [ch][f]
            Wec[ch * FF + f] = (_Float16)We[e];
        }
        if (tid < BB) out[tid] = 0.f;             // zero atomic targets
    }
}

// ---------------------------------------------------------------------------
// chain_kernel: R21-passing structure; only change is the S-phase, which now
// fuses the 3 per-wave rows into one i-loop with 3 interleaved accumulators
// (3-way ILP on the exp chains). MFMA, AT=12 (padded M=16), 256 thr,
// grid 512 = 2 blocks/CU, ballot nv, 4-slot 16KB ring, merged phases.
// ---------------------------------------------------------------------------
#define AT 12

typedef const __attribute__((address_space(1))) void* gp1_t;
typedef __attribute__((address_space(3))) void* lp3_t;
typedef _Float16 h8 __attribute__((ext_vector_type(8)));
typedef float f32x4 __attribute__((ext_vector_type(4)));

__device__ __forceinline__ void stage16(const _Float16* g, _Float16* lds, int tid)
{
    #pragma unroll
    for (int j = 0; j < 4; ++j) {
        const int u = j * 256 + tid;             // 16B units
        __builtin_amdgcn_global_load_lds((gp1_t)(g + (size_t)u * 8),
                                         (lp3_t)(lds + (size_t)u * 8), 16, 0, 0);
    }
}

#define BND(VM) do {                                                        \
    asm volatile("s_waitcnt vmcnt(" VM ") lgkmcnt(0)" ::: "memory");        \
    __builtin_amdgcn_s_barrier();                                           \
    __builtin_amdgcn_sched_barrier(0);                                      \
} while (0)

__device__ __forceinline__ float silu1(float v) { return v / (1.f + __expf(-v)); }

// chunk i -> global source pointer
__device__ __forceinline__ const _Float16* chunk_src(int i, const _Float16* W3c,
    const _Float16* Wa2c, const _Float16* Wo1c)
{
    if (i >= 9) return Wo1c + (size_t)(i - 9) * 8192;
    if (i % 3 == 0) return W3c + (size_t)(i / 3) * 8192;
    return Wa2c + (size_t)(i / 3) * 16384 + (size_t)(i % 3 - 1) * 8192;
}

// B-fragment load from a swizzled chunk: ch = column, KB = k base (0 or 32)
#define LDB(WC, CH, KB) (*(const h8*)&(WC)[(CH) * 64 + (((KB) + lg8) ^ (((CH) & 7) << 3))])
#define MFMA(A, B, C) __builtin_amdgcn_mfma_f32_16x16x32_f16((A), (B), (C), 0, 0, 0)

__global__ __launch_bounds__(256, 2) void chain_kernel(
    const float* __restrict__ X, const float* __restrict__ R,
    const int* __restrict__ batch, const float* __restrict__ be,
    const float* __restrict__ ba1, const float* __restrict__ ba2,
    const float* __restrict__ bo1, const float* __restrict__ Wo2,
    const float* __restrict__ bo2, const _Float16* __restrict__ W3c,
    const _Float16* __restrict__ Wa2c, const _Float16* __restrict__ Wo1c,
    const _Float16* __restrict__ Wec,
    const float* __restrict__ c3, float* __restrict__ out)
{
    __shared__ __align__(16) _Float16 wb[4 * 8192];       // 64KB weight ring
    __shared__ __align__(16) _Float16 sST[16][72];        // 2.3KB S (rows 12-15 zero)
    __shared__ __align__(16) _Float16 thbuf[2 * 16 * 136];// 8.7KB tbT+hbT (sD/sRf alias)
    __shared__ __align__(16) _Float16 sXh[16][32];        // 1KB X f16 (zero-padded)
    __shared__ float po[4][16];
    __shared__ int cpop[4];

    _Float16 (*tbT)[136] = (_Float16(*)[136])thbuf;
    _Float16 (*hbT)[136] = (_Float16(*)[136])(thbuf + 16 * 136);
    float* sD  = (float*)thbuf;          // 1152 floats
    float* sRf = sD + AT * NN;           // 288 floats

    const int tid  = threadIdx.x;
    const int lane = tid & 63;
    const int wv   = tid >> 6;           // wave 0..3
    const int l15  = lane & 15;
    const int lg   = lane >> 4;          // lane group 0..3
    const int lg8  = lg * 8;
    const int lg4  = lg * 4;
    const int bid  = blockIdx.x;
    const int a0   = bid * AT;           // 96 % 12 == 0 -> block within one molecule
    const int b    = a0 / NN;
    const int lbase = a0 - b * NN;

    const int chA = 32 * wv + l15;       // this lane's two output columns
    const int chB = chA + 16;

    // ---- local valid-count ----
    {
        bool v = (tid < NN) && (batch[b * NN + tid] != -1);
        unsigned long long mb = __ballot(v);
        if ((tid & 63) == 0) cpop[wv] = __popcll(mb);
    }
    // ---- stage molecule R, X (f16, zero-padded rows/cols) ----
    for (int t = tid; t < NN * 3; t += 256) sRf[t] = R[b * NN * 3 + t];
    for (int t = tid; t < 512; t += 256) {
        int row = t >> 5, col = t & 31;
        float v = (row < AT && col < FF) ? X[(a0 + row) * FF + col] : 0.f;
        sXh[row][col] = (_Float16)v;
    }
    __syncthreads();
    const int nv = cpop[0] + cpop[1] + cpop[2] + cpop[3];
    const float cb = (float)nv;

    // ---- phase 1: distance table D[j][i] ----
    for (int e = tid; e < AT * NN; e += 256) {
        int j = e / NN, i = e - j * NN;
        float dx = sRf[i * 3 + 0] - sRf[(lbase + j) * 3 + 0];
        float dy = sRf[i * 3 + 1] - sRf[(lbase + j) * 3 + 1];
        float dz = sRf[i * 3 + 2] - sRf[(lbase + j) * 3 + 2];
        sD[e] = sqrtf(dx * dx + dy * dy + dz * dz);
    }
    __syncthreads();   // no DMA outstanding yet

    // ---- bias scalars + embedding B-frag (global loads OLDER than DMAs) ----
    const float be_a = be[chA], be_b = be[chB];
    const float bo1_a = bo1[chA], bo1_b = bo1[chB];
    const float wo2_a = Wo2[chA], wo2_b = Wo2[chB];
    const float bo2R = bo2[0];
    const float c3_0a = c3[chA], c3_0b = c3[chB];
    const float c3_1a = c3[HH + chA], c3_1b = c3[HH + chB];
    const float c3_2a = c3[2 * HH + chA], c3_2b = c3[2 * HH + chB];
    const float ba1_0a = ba1[chA], ba1_0b = ba1[chB];
    const float ba1_1a = ba1[HH + chA], ba1_1b = ba1[HH + chB];
    const float ba1_2a = ba1[2 * HH + chA], ba1_2b = ba1[2 * HH + chB];
    const float ba2_0a = ba2[chA], ba2_0b = ba2[chB];
    const float ba2_1a = ba2[HH + chA], ba2_1b = ba2[HH + chB];
    const float ba2_2a = ba2[2 * HH + chA], ba2_2b = ba2[2 * HH + chB];
    h8 weA = (h8)(_Float16)0.f, weB = (h8)(_Float16)0.f;
    if (lg < 2) {                         // k = lg8..lg8+7 < 16 real features
        weA = *(const h8*)&Wec[chA * FF + lg8];
        weB = *(const h8*)&Wec[chB * FF + lg8];
    }

    // ---- prologue: issue chunks 0..3 ----
    stage16(W3c,          wb + 0 * 8192, tid);   // c0: W3[0]
    stage16(Wa2c,         wb + 1 * 8192, tid);   // c1: Wa2[0] k0-63
    stage16(Wa2c + 8192,  wb + 2 * 8192, tid);   // c2: Wa2[0] k64-127
    stage16(W3c + 8192,   wb + 3 * 8192, tid);   // c3: W3[1]

    // ---- phase 2: sST[j][k] (f16); rows fused for 3-way exp ILP ----
    {
        const float ck = (float)lane * (CUTOFF_F / (float)(KK - 1));
        const int j0 = 3 * wv;
        const float* D0 = sD + (j0 + 0) * NN;
        const float* D1 = sD + (j0 + 1) * NN;
        const float* D2 = sD + (j0 + 2) * NN;
        float a0v = 0.f, a1v = 0.f, a2v = 0.f;
        for (int i = 0; i < nv; ++i) {
            float u0 = D0[i] - ck;
            float u1 = D1[i] - ck;
            float u2 = D2[i] - ck;
            a0v += __expf(-GAMMA_F * u0 * u0);
            a1v += __expf(-GAMMA_F * u1 * u1);
            a2v += __expf(-GAMMA_F * u2 * u2);
        }
        // rows beyond nv contribute garbage -> mask to 0 (prefix validity)
        sST[j0 + 0][lane] = (_Float16)((lbase + j0 + 0 < nv) ? a0v : 0.f);
        sST[j0 + 1][lane] = (_Float16)((lbase + j0 + 1 < nv) ? a1v : 0.f);
        sST[j0 + 2][lane] = (_Float16)((lbase + j0 + 2 < nv) ? a2v : 0.f);
        sST[12 + wv][lane] = (_Float16)0.f;
    }

    // ---- embedding via MFMA: h = X@We + be (K=32, zero-padded) ----
    f32x4 hA, hB;
    {
        f32x4 z = {0.f, 0.f, 0.f, 0.f};
        h8 xa = *(const h8*)&sXh[l15][lg8];
        hA = MFMA(xa, weA, z);
        hB = MFMA(xa, weB, z);
        #pragma unroll
        for (int r = 0; r < 4; ++r) { hA[r] += be_a; hB[r] += be_b; }
    }

    BND("12");   // c0 landed (c1,c2,c3 in flight)

    // ---- layers: 2 phases each (G1 | G2-both) ----
    #pragma unroll 1
    for (int l = 0; l < LL; ++l) {
        const float c3a  = (l == 0) ? c3_0a  : (l == 1) ? c3_1a  : c3_2a;
        const float c3b  = (l == 0) ? c3_0b  : (l == 1) ? c3_1b  : c3_2b;
        const float ba1a = (l == 0) ? ba1_0a : (l == 1) ? ba1_1a : ba1_2a;
        const float ba1b = (l == 0) ? ba1_0b : (l == 1) ? ba1_1b : ba1_2b;
        const float ba2a = (l == 0) ? ba2_0a : (l == 1) ? ba2_1a : ba2_2a;
        const float ba2b = (l == 0) ? ba2_0b : (l == 1) ? ba2_1b : ba2_2b;
        const int c_g1 = 3 * l;

        // G1: agg = S @ W3[l]  (chunk 3l)
        f32x4 accA, accB;
        {
            f32x4 z = {0.f, 0.f, 0.f, 0.f};
            const _Float16* wc = wb + (size_t)(c_g1 & 3) * 8192;
            h8 s0 = *(const h8*)&sST[l15][lg8];
            h8 s1 = *(const h8*)&sST[l15][32 + lg8];
            accA = MFMA(s0, LDB(wc, chA, 0), z);
            accA = MFMA(s1, LDB(wc, chA, 32), accA);
            accB = MFMA(s0, LDB(wc, chB, 0), z);
            accB = MFMA(s1, LDB(wc, chB, 32), accB);
        }
        {   // bias + silu -> tbT (D layout: row = lg4+r, col = chA/chB)
            float biasA = cb * c3a + ba1a, biasB = cb * c3b + ba1b;
            #pragma unroll
            for (int r = 0; r < 4; ++r) {
                tbT[lg4 + r][chA] = (_Float16)silu1(accA[r] + biasA);
                tbT[lg4 + r][chB] = (_Float16)silu1(accB[r] + biasB);
            }
        }
        BND("4");   // chunks 3l+1, 3l+2 landed (one chunk stays in flight)
        { int i = c_g1 + 4; if (i < 11)
            stage16(chunk_src(i, W3c, Wa2c, Wo1c), wb + (size_t)(i & 3) * 8192, tid); }

        // G2: h += t @ Wa2[l]  (chunks 3l+1, 3l+2 in one phase)
        {
            const _Float16* wcA = wb + (size_t)((c_g1 + 1) & 3) * 8192;
            const _Float16* wcB2 = wb + (size_t)((c_g1 + 2) & 3) * 8192;
            h8 t0 = *(const h8*)&tbT[l15][lg8];
            h8 t1 = *(const h8*)&tbT[l15][32 + lg8];
            h8 t2 = *(const h8*)&tbT[l15][64 + lg8];
            h8 t3 = *(const h8*)&tbT[l15][96 + lg8];
            hA = MFMA(t0, LDB(wcA, chA, 0), hA);
            hA = MFMA(t1, LDB(wcA, chA, 32), hA);
            hB = MFMA(t0, LDB(wcA, chB, 0), hB);
            hB = MFMA(t1, LDB(wcA, chB, 32), hB);
            hA = MFMA(t2, LDB(wcB2, chA, 0), hA);
            hA = MFMA(t3, LDB(wcB2, chA, 32), hA);
            hB = MFMA(t2, LDB(wcB2, chB, 0), hB);
            hB = MFMA(t3, LDB(wcB2, chB, 32), hB);
        }
        #pragma unroll
        for (int r = 0; r < 4; ++r) { hA[r] += ba2a; hB[r] += ba2b; }
        if (l == LL - 1) {
            #pragma unroll
            for (int r = 0; r < 4; ++r) {
                hbT[lg4 + r][chA] = (_Float16)hA[r];
                hbT[lg4 + r][chB] = (_Float16)hB[r];
            }
        }
        if (l < LL - 1) {
            BND("4");   // chunk 3l+3 landed
            { int i = c_g1 + 5; if (i < 11)
                stage16(chunk_src(i, W3c, Wa2c, Wo1c), wb + (size_t)(i & 3) * 8192, tid); }
            { int i = c_g1 + 6; if (i < 11)
                stage16(chunk_src(i, W3c, Wa2c, Wo1c), wb + (size_t)(i & 3) * 8192, tid); }
        }
    }

    // ---- head: O = h @ Wo1 (chunks 9 slot1, 10 slot2; both in one phase) ----
    BND("0");
    f32x4 oA, oB;
    {
        f32x4 z = {0.f, 0.f, 0.f, 0.f};
        const _Float16* wc9 = wb + 1 * 8192;
        const _Float16* wc10 = wb + 2 * 8192;
        h8 a0f = *(const h8*)&hbT[l15][lg8];
        h8 a1f = *(const h8*)&hbT[l15][32 + lg8];
        h8 a2f = *(const h8*)&hbT[l15][64 + lg8];
        h8 a3f = *(const h8*)&hbT[l15][96 + lg8];
        oA = MFMA(a0f, LDB(wc9, chA, 0), z);
        oA = MFMA(a1f, LDB(wc9, chA, 32), oA);
        oB = MFMA(a0f, LDB(wc9, chB, 0), z);
        oB = MFMA(a1f, LDB(wc9, chB, 32), oB);
        oA = MFMA(a2f, LDB(wc10, chA, 0), oA);
        oA = MFMA(a3f, LDB(wc10, chA, 32), oA);
        oB = MFMA(a2f, LDB(wc10, chB, 0), oB);
        oB = MFMA(a3f, LDB(wc10, chB, 32), oB);
    }

    // ---- epilogue: silu, Wo2 dot, reduce over channels ----
    float p[4];
    #pragma unroll
    for (int r = 0; r < 4; ++r)
        p[r] = silu1(oA[r] + bo1_a) * wo2_a + silu1(oB[r] + bo1_b) * wo2_b;
    #pragma unroll
    for (int r = 0; r < 4; ++r) {
        p[r] += __shfl_xor(p[r], 1);
        p[r] += __shfl_xor(p[r], 2);
        p[r] += __shfl_xor(p[r], 4);
        p[r] += __shfl_xor(p[r], 8);
    }
    if (l15 == 0) {
        #pragma unroll
        for (int r = 0; r < 4; ++r) po[wv][lg4 + r] = p[r];  // atom = lg4+r
    }
    __syncthreads();
    if (tid == 0) {
        float sum = 0.f;
        #pragma unroll
        for (int j = 0; j < AT; ++j) {
            if (lbase + j < nv)
                sum += po[0][j] + po[1][j] + po[2][j] + po[3][j] + bo2R;
        }
        atomicAdd(out + b, sum / cb);
    }
}

extern "C" void kernel_launch(void* const* d_in, const int* in_sizes, int n_in,
                              void* d_out, int out_size, void* d_ws, size_t ws_size,
                              hipStream_t stream) {
    const float* X     = (const float*)d_in[0];
    const float* R     = (const float*)d_in[1];
    const int*   batch = (const int*)  d_in[2];
    const float* We    = (const float*)d_in[3];
    const float* be    = (const float*)d_in[4];
    const float* Wrbf  = (const float*)d_in[5];
    const float* brbf  = (const float*)d_in[6];
    const float* Wpair = (const float*)d_in[7];
    const float* bpair = (const float*)d_in[8];
    const float* Wa1   = (const float*)d_in[9];
    const float* ba1   = (const float*)d_in[10];
    const float* Wa2   = (const float*)d_in[11];
    const float* ba2   = (const float*)d_in[12];
    const float* Wo1   = (const float*)d_in[13];
    const float* bo1   = (const float*)d_in[14];
    const float* Wo2   = (const float*)d_in[15];
    const float* bo2   = (const float*)d_in[16];

    char* wsb = (char*)d_ws;
    _Float16* W3c  = (_Float16*)wsb;                         // 24576 f16 = 49152 B
    _Float16* Wa2c = (_Float16*)(wsb + 49152);               // 49152 f16 = 98304 B
    _Float16* Wo1c = (_Float16*)(wsb + 147456);              // 16384 f16 = 32768 B
    _Float16* Wec  = (_Float16*)(wsb + 180224);              // 2048 f16  = 4096 B
    float*    c3   = (float*)(wsb + 184320);                 // 384 f32   = 1536 B
    float*    out  = (float*)d_out;

    hipLaunchKernelGGL(pre_kernel,
                       dim3(W3_BLOCKS + WA2_CP + WO1_CP + WE_CP), dim3(512),
                       0, stream, Wrbf, brbf, Wpair, bpair, Wa1, Wa2, Wo1, We,
                       W3c, c3, Wa2c, Wo1c, Wec, out);
    hipLaunchKernelGGL(chain_kernel, dim3(BB * NN / AT), dim3(256), 0, stream,
                       X, R, batch, be, ba1, ba2, bo1, Wo2, bo2,
                       W3c, Wa2c, Wo1c, Wec, c3, out);
}